// Round 24
// baseline (455.378 us; speedup 1.0000x reference)
//
#include <hip/hip_runtime.h>
#include <hip/hip_bf16.h>
#include <math.h>

#define NN 100000
#define EE 3200000
#define ET (EE + NN)          // edges incl. self loops
#define FIN 1433
#define KPAD 1440
#define NT 45                 // K tiles of 32
#define F1 64
#define F2 7
#define G1B 782               // gemm1 blocks (ceil(NN/128))
#define CAP 128               // padded CSR capacity per node
#define BINS 200              // dst>>9 -> 0..195 (padded)
#define HB1 128               // hist blocks (512 thr each)
#define CH_E 25782            // ceil(ET/HB1)
#define NB4 196               // bucket-group blocks ((NN+511)>>9)
#define A1B 3125              // att1 blocks (NN*8/256)

typedef __attribute__((ext_vector_type(8))) short short8;
typedef __attribute__((ext_vector_type(4))) float f32x4;
typedef __attribute__((address_space(3))) unsigned int u32_lds;
typedef __attribute__((address_space(1))) const unsigned int u32_glb;

static __device__ __forceinline__ unsigned short f2bf(float f) {
  __hip_bfloat16 h = __float2bfloat16(f);
  return *reinterpret_cast<unsigned short*>(&h);
}
static __device__ __forceinline__ float bf2f(unsigned short u) {
  return __uint_as_float((unsigned int)u << 16);
}

// ---------------- prep: W1^T bf16 (padded) ----------------
__global__ __launch_bounds__(256) void k_prep(const float* __restrict__ W1,
                                              unsigned short* __restrict__ WT) {
  int i = blockIdx.x * 256 + threadIdx.x;
  if (i < F1 * KPAD) {
    int c = i / KPAD, k = i - c * KPAD;
    WT[i] = f2bf((k < FIN) ? W1[k * F1 + c] : 0.f);
  }
}

// ---------------- fuse1: gemm1 BM=128/512thr (blocks 0..G1B) || B1 histogram ----------------
// 8 waves x 16 rows each; LDS 40960 B -> exactly 4 blocks/CU = 32 waves (100%).
// Wave formulas identical to the verified BM=64 kernel (r = wid*16+l15 etc).
#define BM 128
#define TILEA 16384           // 128 rows x 32 k x f32
#define TILEB 4096            // 64 cols x 32 k bf16
#define BUFB (TILEA + TILEB)  // 20480

__global__ __launch_bounds__(512) void k_fuse1(const float* __restrict__ X,
                                               const unsigned short* __restrict__ WT,
                                               unsigned short* __restrict__ Hb,
                                               const int* __restrict__ ei,
                                               int* __restrict__ histM) {
  __shared__ __align__(16) char smem[2 * BUFB];
  if (blockIdx.x >= G1B) {
    // ---- B1: per-block LDS histogram of dst buckets (LDS atomics only) ----
    int* hist = (int*)smem;
    const int b = blockIdx.x - G1B;
    for (int i = threadIdx.x; i < BINS; i += 512) hist[i] = 0;
    __syncthreads();
    const int e0 = b * CH_E, e1 = min(e0 + CH_E, ET);
    for (int e = e0 + threadIdx.x; e < e1; e += 512) {
      int dst = (e < EE) ? ei[EE + e] : (e - EE);
      atomicAdd(&hist[dst >> 9], 1);
    }
    __syncthreads();
    for (int i = threadIdx.x; i < BINS; i += 512) histM[b * BINS + i] = hist[i];
    return;
  }
  const int tid = threadIdx.x;
  const int lane = tid & 63;
  const int wid = tid >> 6;           // 0..7
  const int row0 = blockIdx.x * BM;
  const int l15 = lane & 15, l4 = lane >> 4;

  // A staging: 128 rows x 8 chunks = 1024 chunks; 2 per thread (q=0,1)
  const int lrq = tid >> 3;           // 0..63
  const int mq = tid & 7;             // lds 16-B chunk slot
  const char* Xb = (const char*)X;
  size_t aoff[2];
#pragma unroll
  for (int q = 0; q < 2; ++q) {
    int lr = q * 64 + lrq;
    int gr = row0 + lr; if (gr >= NN) gr = NN - 1;
    int c = mq ^ (lr & 7);            // source chunk (inverse swizzle)
    aoff[q] = (size_t)gr * (FIN * 4) + (size_t)c * 16;
  }
  // B staging: 256 chunks; threads 0..255 stage one each
  const unsigned short* bsrc =
      WT + (tid >> 2) * KPAD + (((tid & 3) ^ ((tid >> 3) & 3)) << 3);

  f32x4 acc[4];
#pragma unroll
  for (int fc = 0; fc < 4; ++fc) acc[fc] = 0.f;

  auto gstage = [&](int k0, char* buf) {
#pragma unroll
    for (int q = 0; q < 2; ++q) {
      __builtin_amdgcn_global_load_lds(
          (u32_glb*)(Xb + aoff[q] + (size_t)k0 * 4),
          (u32_lds*)(buf + q * 8192 + wid * 1024), 16, 0, 0);
    }
  };

  gstage(0, smem);
  if (tid < 256) {
    short8 b0 = *(const short8*)(bsrc + 0);
    *(short8*)(smem + TILEA + tid * 16) = b0;
  }
  __syncthreads();

  int cur = 0;
  for (int t = 0; t < NT; ++t) {
    char* buf = smem + cur * BUFB;
    char* nbuf = smem + (cur ^ 1) * BUFB;
    const bool have_next = (t + 1 < NT);
    const bool tail = (t + 1 == NT - 1);
    short8 bnext;
    f32x4 atail[2];
    if (have_next) {
      if (!tail) {
        gstage((t + 1) * 32, nbuf);
      } else {
        // last k-tile (k0=1408): predicated register path (avoids OOB)
#pragma unroll
        for (int q = 0; q < 2; ++q) {
          int lr = q * 64 + lrq;
          int gr = row0 + lr; if (gr >= NN) gr = NN - 1;
          int c = mq ^ (lr & 7);
          int kb = (NT - 1) * 32 + c * 4;
          const float* xp = X + (size_t)gr * FIN + kb;
#pragma unroll
          for (int j = 0; j < 4; ++j)
            atail[q][j] = (kb + j < FIN) ? xp[j] : 0.f;
        }
      }
      if (tid < 256) bnext = *(const short8*)(bsrc + (t + 1) * 32);
    }

    // A frag: row = wid*16 + l15, source chunks 2*l4, 2*l4+1 (swizzled slots)
    short8 a;
    {
      const int r = wid * 16 + l15;
      const int sz = l15 & 7;         // r&7 == l15&7
      f32x4 a0 = *(const f32x4*)(buf + r * 128 + ((2 * l4) ^ sz) * 16);
      f32x4 a1 = *(const f32x4*)(buf + r * 128 + ((2 * l4 + 1) ^ sz) * 16);
#pragma unroll
      for (int j = 0; j < 4; ++j) {
        a[j] = (short)f2bf(a0[j]);
        a[4 + j] = (short)f2bf(a1[j]);
      }
    }
#pragma unroll
    for (int fc = 0; fc < 4; ++fc) {
      int c = fc * 16 + l15;
      int jp = l4 ^ ((c >> 1) & 3);
      short8 b = *(const short8*)(buf + TILEA + c * 64 + jp * 16);
      acc[fc] = __builtin_amdgcn_mfma_f32_16x16x32_bf16(a, b, acc[fc], 0, 0, 0);
    }

    if (have_next) {
      if (tail) {
#pragma unroll
        for (int q = 0; q < 2; ++q)
          *(f32x4*)(nbuf + (q * 64 + lrq) * 128 + mq * 16) = atail[q];
      }
      if (tid < 256) *(short8*)(nbuf + TILEA + tid * 16) = bnext;
    }
    __syncthreads();
    cur ^= 1;
  }

  // epilogue: C/D layout col=lane&15, row=(lane>>4)*4+reg; store bf16
  const int rbase = row0 + wid * 16 + l4 * 4;
#pragma unroll
  for (int j = 0; j < 4; ++j) {
    int r = rbase + j;
    if (r < NN) {
#pragma unroll
      for (int fc = 0; fc < 4; ++fc)
        Hb[(size_t)r * F1 + fc * 16 + l15] = f2bf(acc[fc][j]);
    }
  }
}

// ---------------- B2: scan histM -> exact per-(block,bin) offsets ----------------
__global__ __launch_bounds__(256) void k_scanM(int* __restrict__ histM,
                                               int* __restrict__ binS,
                                               int* __restrict__ binE) {
  __shared__ int s[256];
  const int t = threadIdx.x;
  int total = 0;
  if (t < BINS)
    for (int b = 0; b < HB1; ++b) total += histM[b * BINS + t];
  s[t] = total;
  __syncthreads();
  for (int off = 1; off < 256; off <<= 1) {
    int v = s[t];
    int u = (t >= off) ? s[t - off] : 0;
    __syncthreads();
    s[t] = v + u;
    __syncthreads();
  }
  if (t < BINS) {
    int run = s[t] - total;            // exclusive prefix
    binS[t] = run;
    for (int b = 0; b < HB1; ++b) {
      int h = histM[b * BINS + t];
      histM[b * BINS + t] = run;
      run += h;
    }
    binE[t] = run;
  }
}

// ---------------- B3: bin edges (plain stores, LDS cursors) ----------------
__global__ __launch_bounds__(256) void k_bin(const int* __restrict__ ei,
                                             const int* __restrict__ histM,
                                             unsigned int* __restrict__ binned) {
  __shared__ int cur[BINS];
  const int b = blockIdx.x;
  for (int i = threadIdx.x; i < BINS; i += 256) cur[i] = histM[b * BINS + i];
  __syncthreads();
  const int e0 = b * CH_E, e1 = min(e0 + CH_E, ET);
  for (int e = e0 + threadIdx.x; e < e1; e += 256) {
    int dst = (e < EE) ? ei[EE + e] : (e - EE);
    int src = (e < EE) ? ei[e] : dst;
    int pos = atomicAdd(&cur[dst >> 9], 1);        // LDS atomic
    binned[pos] = ((unsigned)(dst & 511) << 17) | (unsigned)src;
  }
}

// ---------------- fuse2: att1 (blocks 0..A1B) || B4 bucket-group ----------------
__global__ __launch_bounds__(256) void k_fuse2(const unsigned short* __restrict__ Hb,
                                               const float* __restrict__ attS,
                                               const float* __restrict__ attD,
                                               float* __restrict__ aS,
                                               float* __restrict__ aD,
                                               const unsigned int* __restrict__ binned,
                                               const int* __restrict__ binS,
                                               const int* __restrict__ binE,
                                               int* __restrict__ cnt,
                                               int* __restrict__ csr) {
  if (blockIdx.x >= A1B) {
    // ---- B4: group one bucket's edges into padded CSR (LDS atomics only) ----
    __shared__ int lcnt[512];
    const int g = blockIdx.x - A1B;
    for (int i = threadIdx.x; i < 512; i += 256) lcnt[i] = 0;
    __syncthreads();
    const int s0 = binS[g], s1 = binE[g];
    const int nbase = g << 9;
    for (int i = s0 + threadIdx.x; i < s1; i += 256) {
      unsigned v = binned[i];
      int ld = v >> 17;
      int src = (int)(v & 0x1FFFFu);
      int pos = atomicAdd(&lcnt[ld], 1);           // LDS atomic
      csr[((size_t)(nbase + ld) << 7) + pos] = src;
    }
    __syncthreads();
    for (int i = threadIdx.x; i < 512; i += 256) {
      int n = nbase + i;
      if (n < NN) cnt[n] = lcnt[i];
    }
    return;
  }
  // ---- att1: per-node attention scores (8 threads/node) ----
  __shared__ float s_s[64], s_d[64];
  if (threadIdx.x < 64) { s_s[threadIdx.x] = attS[threadIdx.x]; s_d[threadIdx.x] = attD[threadIdx.x]; }
  __syncthreads();
  int idx = blockIdx.x * 256 + threadIdx.x;
  int n = idx >> 3, h = idx & 7;
  if (n >= NN) return;
  short8 v8 = *(const short8*)(Hb + (size_t)n * 64 + h * 8);
  float ss = 0.f, dd = 0.f;
#pragma unroll
  for (int c = 0; c < 8; ++c) {
    float v = bf2f((unsigned short)v8[c]);
    ss = fmaf(v, s_s[h * 8 + c], ss);
    dd = fmaf(v, s_d[h * 8 + c], dd);
  }
  aS[n * 8 + h] = ss;
  aD[n * 8 + h] = dd;
}

// ---------------- agg1 + fused gemm2/att2: wave per node, 8 edges x 8 heads ----
__global__ __launch_bounds__(256) void k_agg1(const unsigned short* __restrict__ Hb,
                                              const float* __restrict__ aS,
                                              const float* __restrict__ aD,
                                              const int* __restrict__ cnt,
                                              const int* __restrict__ csr,
                                              const float* __restrict__ b1,
                                              const float* __restrict__ W2,
                                              const float* __restrict__ s2,
                                              const float* __restrict__ d2,
                                              unsigned short* __restrict__ H2b,
                                              float* __restrict__ aD2) {
  __shared__ float s_w2[448];
  __shared__ float s_ss[7], s_dd[7];
  __shared__ float s_b1[64];
  for (int i = threadIdx.x; i < 448; i += 256) s_w2[i] = W2[i];
  if (threadIdx.x < 7) { s_ss[threadIdx.x] = s2[threadIdx.x]; s_dd[threadIdx.x] = d2[threadIdx.x]; }
  if (threadIdx.x < 64) s_b1[threadIdx.x] = b1[threadIdx.x];
  __syncthreads();

  const int wv = threadIdx.x >> 6, lane = threadIdx.x & 63;
  const int n = blockIdx.x * 4 + wv;
  if (n >= NN) return;
  const int eg = lane >> 3, q = lane & 7;
  const float adv = aD[n * 8 + q];
  const int beg = n << 7;
  const int deg = cnt[n];
  float acc[8] = {};
  float den = 0.f;
#pragma unroll 2
  for (int i = eg; i < deg; i += 8) {
    int s = csr[beg + i];                 // broadcast within eg-group
    float e = aS[s * 8 + q] + adv;
    e = (e > 0.f) ? e : 0.2f * e;         // leaky_relu
    float w = __expf(e);                  // max-shift unnecessary (|e| bounded)
    den += w;
    short8 hv = *(const short8*)(Hb + (size_t)s * 64 + q * 8);
#pragma unroll
    for (int c = 0; c < 8; ++c)
      acc[c] = fmaf(w, bf2f((unsigned short)hv[c]), acc[c]);
  }
#pragma unroll
  for (int off = 8; off < 64; off <<= 1) {
    den += __shfl_xor(den, off, 64);
#pragma unroll
    for (int c = 0; c < 8; ++c) acc[c] += __shfl_xor(acc[c], off, 64);
  }
  if (eg == 0) {                          // lanes 0..7: lane q holds head q's 8 ch
    float inv = 1.f / den;
    float v[8];
#pragma unroll
    for (int c = 0; c < 8; ++c) {
      float t = acc[c] * inv + s_b1[q * 8 + c];
      v[c] = (t > 0.f) ? t : (__expf(t) - 1.f);   // ELU
    }
    // fused gemm2: partial h2[j] = sum_c v[c] * W2[q*8+c][j]
    float p[7] = {};
#pragma unroll
    for (int c = 0; c < 8; ++c) {
      const float* wr = &s_w2[(q * 8 + c) * 7];
#pragma unroll
      for (int j = 0; j < 7; ++j) p[j] = fmaf(v[c], wr[j], p[j]);
    }
#pragma unroll
    for (int off = 1; off < 8; off <<= 1) {
#pragma unroll
      for (int j = 0; j < 7; ++j) p[j] += __shfl_xor(p[j], off, 64);
    }
    if (q == 0) {
      float s = 0.f, d = 0.f;
      short8 row;
#pragma unroll
      for (int j = 0; j < 7; ++j) {
        row[j] = (short)f2bf(p[j]);
        s = fmaf(p[j], s_ss[j], s);
        d = fmaf(p[j], s_dd[j], d);
      }
      row[7] = (short)f2bf(s);            // a_src score packed in slot 7
      *(short8*)(H2b + (size_t)n * 8) = row;
      aD2[n] = d;
    }
  }
}

// ---------------- aggregation layer 2: wave per node, lanes split edges ----------------
__global__ __launch_bounds__(256) void k_agg2(const unsigned short* __restrict__ H2b,
                                              const float* __restrict__ aD2,
                                              const int* __restrict__ cnt,
                                              const int* __restrict__ csr,
                                              const float* __restrict__ b2,
                                              float* __restrict__ out) {
  const int wv = threadIdx.x >> 6, lane = threadIdx.x & 63;
  const int n = blockIdx.x * 4 + wv;
  if (n >= NN) return;
  const float adv = aD2[n];
  const int beg = n << 7;
  const int deg = cnt[n];
  float acc[7] = {};
  float den = 0.f;
  for (int j = lane; j < deg; j += 64) {
    int s = csr[beg + j];
    short8 hv = *(const short8*)(H2b + (size_t)s * 8);
    float e = bf2f((unsigned short)hv[7]) + adv;
    e = (e > 0.f) ? e : 0.2f * e;
    float wgt = __expf(e);
    den += wgt;
#pragma unroll
    for (int c = 0; c < 7; ++c)
      acc[c] = fmaf(wgt, bf2f((unsigned short)hv[c]), acc[c]);
  }
#pragma unroll
  for (int off = 32; off > 0; off >>= 1) {
    den += __shfl_xor(den, off, 64);
#pragma unroll
    for (int c = 0; c < 7; ++c) acc[c] += __shfl_xor(acc[c], off, 64);
  }
  if (lane == 0) {
    float inv = 1.f / den;
    float v[7];
    float m = -1e30f;
#pragma unroll
    for (int c = 0; c < 7; ++c) { v[c] = acc[c] * inv + b2[c]; m = fmaxf(m, v[c]); }
    float se = 0.f;
#pragma unroll
    for (int c = 0; c < 7; ++c) se += __expf(v[c] - m);
    float lse = m + __logf(se);
#pragma unroll
    for (int c = 0; c < 7; ++c) out[n * 7 + c] = v[c] - lse;
  }
}

extern "C" void kernel_launch(void* const* d_in, const int* in_sizes, int n_in,
                              void* d_out, int out_size, void* d_ws, size_t ws_size,
                              hipStream_t stream) {
  const float* x   = (const float*)d_in[0];
  const int*   ei  = (const int*)d_in[1];
  const float* W1  = (const float*)d_in[2];
  const float* as1 = (const float*)d_in[3];
  const float* ad1 = (const float*)d_in[4];
  const float* b1  = (const float*)d_in[5];
  const float* W2  = (const float*)d_in[6];
  const float* as2 = (const float*)d_in[7];
  const float* ad2 = (const float*)d_in[8];
  const float* b2  = (const float*)d_in[9];
  float* out = (float*)d_out;

  char* ws = (char*)d_ws;
  size_t off = 0;
  auto alloc = [&](size_t bytes) {
    void* p = ws + off;
    off += (bytes + 255) & ~(size_t)255;
    return p;
  };
  unsigned short* h1b = (unsigned short*)alloc((size_t)NN * 64 * 2);
  float* sc1    = (float*)alloc((size_t)NN * 8 * 4);
  float* dc1    = (float*)alloc((size_t)NN * 8 * 4);
  unsigned short* h2b = (unsigned short*)alloc((size_t)NN * 8 * 2);
  float* dc2    = (float*)alloc((size_t)NN * 4);
  int*   cnt    = (int*)alloc((size_t)NN * 4);
  int*   csr    = (int*)alloc((size_t)NN * CAP * 4);
  int*   histM  = (int*)alloc((size_t)HB1 * BINS * 4);
  int*   binS   = (int*)alloc((size_t)BINS * 4);
  int*   binE   = (int*)alloc((size_t)BINS * 4);
  unsigned int* binned = (unsigned int*)alloc((size_t)ET * 4);
  unsigned short* w1t = (unsigned short*)alloc((size_t)F1 * KPAD * 2);

  // prep: W1^T
  k_prep<<<(F1 * KPAD + 255) / 256, 256, 0, stream>>>(W1, w1t);

  // gemm1 (BM=128, 512thr, 4 blocks/CU = 100% occ) || B1 bucket histogram
  k_fuse1<<<G1B + HB1, 512, 0, stream>>>(x, w1t, h1b, ei, histM);

  // B2: offsets
  k_scanM<<<1, 256, 0, stream>>>(histM, binS, binE);

  // B3: bin edges (no global atomics)
  k_bin<<<HB1, 256, 0, stream>>>(ei, histM, binned);

  // att1 || B4 bucket-group -> padded CSR
  k_fuse2<<<A1B + NB4, 256, 0, stream>>>(h1b, as1, ad1, sc1, dc1,
                                         binned, binS, binE, cnt, csr);

  // agg1 + fused gemm2/att2
  k_agg1<<<(NN + 3) / 4, 256, 0, stream>>>(h1b, sc1, dc1, cnt, csr, b1,
                                           W2, as2, ad2, h2b, dc2);

  // agg2 + log_softmax
  k_agg2<<<(NN + 3) / 4, 256, 0, stream>>>(h2b, dc2, cnt, csr, b2, out);
}

// Round 25
// 451.015 us; speedup vs baseline: 1.0097x; 1.0097x over previous
//
#include <hip/hip_runtime.h>
#include <hip/hip_bf16.h>
#include <math.h>

#define NN 100000
#define EE 3200000
#define ET (EE + NN)          // edges incl. self loops
#define FIN 1433
#define KPAD 1440
#define NT 45                 // K tiles of 32
#define F1 64
#define F2 7
#define G1B 1563              // gemm1 blocks (ceil(NN/64))
#define CAP 128               // padded CSR capacity per node
#define BINS 200              // dst>>9 -> 0..195 (padded)
#define SB1 256               // binning blocks
#define CH_E 12891            // ceil(ET/SB1)
#define NB4 196               // bucket-group blocks ((NN+511)>>9)
#define A1B 3125              // att1 blocks (NN*8/256)

typedef __attribute__((ext_vector_type(8))) short short8;
typedef __attribute__((ext_vector_type(4))) float f32x4;
typedef __attribute__((address_space(3))) unsigned int u32_lds;
typedef __attribute__((address_space(1))) const unsigned int u32_glb;

static __device__ __forceinline__ unsigned short f2bf(float f) {
  __hip_bfloat16 h = __float2bfloat16(f);
  return *reinterpret_cast<unsigned short*>(&h);
}
static __device__ __forceinline__ float bf2f(unsigned short u) {
  return __uint_as_float((unsigned int)u << 16);
}

// ---------------- prep: W1^T bf16 (padded) ----------------
__global__ __launch_bounds__(256) void k_prep(const float* __restrict__ W1,
                                              unsigned short* __restrict__ WT) {
  int i = blockIdx.x * 256 + threadIdx.x;
  if (i < F1 * KPAD) {
    int c = i / KPAD, k = i - c * KPAD;
    WT[i] = f2bf((k < FIN) ? W1[k * F1 + c] : 0.f);
  }
}

// ---------------- fuse1: gemm1 BM=64, B-from-L2 (blocks 0..G1B) || B1 histogram ----------------
// R22's verified A-path (gload_lds, source-swizzled) + R20's verified
// B-direct-from-L2 read. LDS = A only: dbuf 16.4 KB -> 8 blocks/CU = 32 waves
// (100% occupancy) at 4-wave barrier width.
#define BM 64
#define TILEA 8192            // 64 rows x 32 k x f32
#define BUFB TILEA            // A only

__global__ __launch_bounds__(256) void k_fuse1(const float* __restrict__ X,
                                               const unsigned short* __restrict__ WT,
                                               unsigned short* __restrict__ Hb,
                                               const int* __restrict__ ei,
                                               int* __restrict__ histM) {
  if (blockIdx.x >= G1B) {
    // ---- B1: per-block LDS histogram of dst buckets (LDS atomics only) ----
    __shared__ int hist[BINS];
    const int b = blockIdx.x - G1B;
    for (int i = threadIdx.x; i < BINS; i += 256) hist[i] = 0;
    __syncthreads();
    const int e0 = b * CH_E, e1 = min(e0 + CH_E, ET);
    for (int e = e0 + threadIdx.x; e < e1; e += 256) {
      int dst = (e < EE) ? ei[EE + e] : (e - EE);
      atomicAdd(&hist[dst >> 9], 1);
    }
    __syncthreads();
    for (int i = threadIdx.x; i < BINS; i += 256) histM[b * BINS + i] = hist[i];
    return;
  }
  __shared__ __align__(16) char smem[2 * BUFB];
  const int tid = threadIdx.x;
  const int lane = tid & 63;
  const int wid = tid >> 6;
  const int row0 = blockIdx.x * BM;
  const int l15 = lane & 15, l4 = lane >> 4;

  // A staging: 64 rows x 8 chunks = 512 chunks; 2 per thread (q=0,1)
  const int lrq = tid >> 3;          // 0..31
  const int mq = tid & 7;            // lds 16-B chunk slot
  const char* Xb = (const char*)X;
  size_t aoff[2];
#pragma unroll
  for (int q = 0; q < 2; ++q) {
    int lr = q * 32 + lrq;
    int gr = row0 + lr; if (gr >= NN) gr = NN - 1;
    int c = mq ^ (lr & 7);           // source chunk (inverse swizzle)
    aoff[q] = (size_t)gr * (FIN * 4) + (size_t)c * 16;
  }

  f32x4 acc[4];
#pragma unroll
  for (int fc = 0; fc < 4; ++fc) acc[fc] = 0.f;

  auto gstage = [&](int k0, char* buf) {
#pragma unroll
    for (int q = 0; q < 2; ++q) {
      __builtin_amdgcn_global_load_lds(
          (u32_glb*)(Xb + aoff[q] + (size_t)k0 * 4),
          (u32_lds*)(buf + q * 4096 + wid * 1024), 16, 0, 0);
    }
  };

  gstage(0, smem);
  __syncthreads();

  int cur = 0;
  for (int t = 0; t < NT; ++t) {
    char* buf = smem + cur * BUFB;
    char* nbuf = smem + (cur ^ 1) * BUFB;
    const bool have_next = (t + 1 < NT);
    const bool tail = (t + 1 == NT - 1);
    f32x4 atail[2];
    if (have_next) {
      if (!tail) {
        gstage((t + 1) * 32, nbuf);
      } else {
        // last k-tile (k0=1408): predicated register path (avoids OOB)
#pragma unroll
        for (int q = 0; q < 2; ++q) {
          int lr = q * 32 + lrq;
          int gr = row0 + lr; if (gr >= NN) gr = NN - 1;
          int c = mq ^ (lr & 7);
          int kb = (NT - 1) * 32 + c * 4;
          const float* xp = X + (size_t)gr * FIN + kb;
#pragma unroll
          for (int j = 0; j < 4; ++j)
            atail[q][j] = (kb + j < FIN) ? xp[j] : 0.f;
        }
      }
    }

    // A frag: row = wid*16 + l15, source chunks 2*l4, 2*l4+1 (swizzled slots)
    short8 a;
    {
      const int r = wid * 16 + l15;
      const int sz = l15 & 7;       // r&7 == l15&7
      f32x4 a0 = *(const f32x4*)(buf + r * 128 + ((2 * l4) ^ sz) * 16);
      f32x4 a1 = *(const f32x4*)(buf + r * 128 + ((2 * l4 + 1) ^ sz) * 16);
#pragma unroll
      for (int j = 0; j < 4; ++j) {
        a[j] = (short)f2bf(a0[j]);
        a[4 + j] = (short)f2bf(a1[j]);
      }
    }
    const int k0 = t * 32;
#pragma unroll
    for (int fc = 0; fc < 4; ++fc) {
      int c = fc * 16 + l15;
      short8 b = *(const short8*)(WT + (size_t)c * KPAD + k0 + l4 * 8);
      acc[fc] = __builtin_amdgcn_mfma_f32_16x16x32_bf16(a, b, acc[fc], 0, 0, 0);
    }

    if (have_next && tail) {
#pragma unroll
      for (int q = 0; q < 2; ++q)
        *(f32x4*)(nbuf + (q * 32 + lrq) * 128 + mq * 16) = atail[q];
    }
    __syncthreads();
    cur ^= 1;
  }

  // epilogue: C/D layout col=lane&15, row=(lane>>4)*4+reg; store bf16
  const int rbase = row0 + wid * 16 + l4 * 4;
#pragma unroll
  for (int j = 0; j < 4; ++j) {
    int r = rbase + j;
    if (r < NN) {
#pragma unroll
      for (int fc = 0; fc < 4; ++fc)
        Hb[(size_t)r * F1 + fc * 16 + l15] = f2bf(acc[fc][j]);
    }
  }
}

// ---------------- B2: scan histM -> exact per-(block,bin) offsets ----------------
__global__ __launch_bounds__(256) void k_scanM(int* __restrict__ histM,
                                               int* __restrict__ binS,
                                               int* __restrict__ binE) {
  __shared__ int s[256];
  const int t = threadIdx.x;
  int total = 0;
  if (t < BINS)
    for (int b = 0; b < SB1; ++b) total += histM[b * BINS + t];
  s[t] = total;
  __syncthreads();
  for (int off = 1; off < 256; off <<= 1) {
    int v = s[t];
    int u = (t >= off) ? s[t - off] : 0;
    __syncthreads();
    s[t] = v + u;
    __syncthreads();
  }
  if (t < BINS) {
    int run = s[t] - total;            // exclusive prefix
    binS[t] = run;
    for (int b = 0; b < SB1; ++b) {
      int h = histM[b * BINS + t];
      histM[b * BINS + t] = run;
      run += h;
    }
    binE[t] = run;
  }
}

// ---------------- B3: bin edges (plain stores, LDS cursors) ----------------
__global__ __launch_bounds__(256) void k_bin(const int* __restrict__ ei,
                                             const int* __restrict__ histM,
                                             unsigned int* __restrict__ binned) {
  __shared__ int cur[BINS];
  const int b = blockIdx.x;
  for (int i = threadIdx.x; i < BINS; i += 256) cur[i] = histM[b * BINS + i];
  __syncthreads();
  const int e0 = b * CH_E, e1 = min(e0 + CH_E, ET);
  for (int e = e0 + threadIdx.x; e < e1; e += 256) {
    int dst = (e < EE) ? ei[EE + e] : (e - EE);
    int src = (e < EE) ? ei[e] : dst;
    int pos = atomicAdd(&cur[dst >> 9], 1);        // LDS atomic
    binned[pos] = ((unsigned)(dst & 511) << 17) | (unsigned)src;
  }
}

// ---------------- fuse2: att1 (blocks 0..A1B) || B4 bucket-group ----------------
__global__ __launch_bounds__(256) void k_fuse2(const unsigned short* __restrict__ Hb,
                                               const float* __restrict__ attS,
                                               const float* __restrict__ attD,
                                               float* __restrict__ aS,
                                               float* __restrict__ aD,
                                               const unsigned int* __restrict__ binned,
                                               const int* __restrict__ binS,
                                               const int* __restrict__ binE,
                                               int* __restrict__ cnt,
                                               int* __restrict__ csr) {
  if (blockIdx.x >= A1B) {
    // ---- B4: group one bucket's edges into padded CSR (LDS atomics only) ----
    __shared__ int lcnt[512];
    const int g = blockIdx.x - A1B;
    for (int i = threadIdx.x; i < 512; i += 256) lcnt[i] = 0;
    __syncthreads();
    const int s0 = binS[g], s1 = binE[g];
    const int nbase = g << 9;
    for (int i = s0 + threadIdx.x; i < s1; i += 256) {
      unsigned v = binned[i];
      int ld = v >> 17;
      int src = (int)(v & 0x1FFFFu);
      int pos = atomicAdd(&lcnt[ld], 1);           // LDS atomic
      csr[((size_t)(nbase + ld) << 7) + pos] = src;
    }
    __syncthreads();
    for (int i = threadIdx.x; i < 512; i += 256) {
      int n = nbase + i;
      if (n < NN) cnt[n] = lcnt[i];
    }
    return;
  }
  // ---- att1: per-node attention scores (8 threads/node) ----
  __shared__ float s_s[64], s_d[64];
  if (threadIdx.x < 64) { s_s[threadIdx.x] = attS[threadIdx.x]; s_d[threadIdx.x] = attD[threadIdx.x]; }
  __syncthreads();
  int idx = blockIdx.x * 256 + threadIdx.x;
  int n = idx >> 3, h = idx & 7;
  if (n >= NN) return;
  short8 v8 = *(const short8*)(Hb + (size_t)n * 64 + h * 8);
  float ss = 0.f, dd = 0.f;
#pragma unroll
  for (int c = 0; c < 8; ++c) {
    float v = bf2f((unsigned short)v8[c]);
    ss = fmaf(v, s_s[h * 8 + c], ss);
    dd = fmaf(v, s_d[h * 8 + c], dd);
  }
  aS[n * 8 + h] = ss;
  aD[n * 8 + h] = dd;
}

// ---------------- agg1 + fused gemm2/att2: wave per node, 8 edges x 8 heads ----
__global__ __launch_bounds__(256) void k_agg1(const unsigned short* __restrict__ Hb,
                                              const float* __restrict__ aS,
                                              const float* __restrict__ aD,
                                              const int* __restrict__ cnt,
                                              const int* __restrict__ csr,
                                              const float* __restrict__ b1,
                                              const float* __restrict__ W2,
                                              const float* __restrict__ s2,
                                              const float* __restrict__ d2,
                                              unsigned short* __restrict__ H2b,
                                              float* __restrict__ aD2) {
  __shared__ float s_w2[448];
  __shared__ float s_ss[7], s_dd[7];
  __shared__ float s_b1[64];
  for (int i = threadIdx.x; i < 448; i += 256) s_w2[i] = W2[i];
  if (threadIdx.x < 7) { s_ss[threadIdx.x] = s2[threadIdx.x]; s_dd[threadIdx.x] = d2[threadIdx.x]; }
  if (threadIdx.x < 64) s_b1[threadIdx.x] = b1[threadIdx.x];
  __syncthreads();

  const int wv = threadIdx.x >> 6, lane = threadIdx.x & 63;
  const int n = blockIdx.x * 4 + wv;
  if (n >= NN) return;
  const int eg = lane >> 3, q = lane & 7;
  const float adv = aD[n * 8 + q];
  const int beg = n << 7;
  const int deg = cnt[n];
  float acc[8] = {};
  float den = 0.f;
#pragma unroll 2
  for (int i = eg; i < deg; i += 8) {
    int s = csr[beg + i];                 // broadcast within eg-group
    float e = aS[s * 8 + q] + adv;
    e = (e > 0.f) ? e : 0.2f * e;         // leaky_relu
    float w = __expf(e);                  // max-shift unnecessary (|e| bounded)
    den += w;
    short8 hv = *(const short8*)(Hb + (size_t)s * 64 + q * 8);
#pragma unroll
    for (int c = 0; c < 8; ++c)
      acc[c] = fmaf(w, bf2f((unsigned short)hv[c]), acc[c]);
  }
#pragma unroll
  for (int off = 8; off < 64; off <<= 1) {
    den += __shfl_xor(den, off, 64);
#pragma unroll
    for (int c = 0; c < 8; ++c) acc[c] += __shfl_xor(acc[c], off, 64);
  }
  if (eg == 0) {                          // lanes 0..7: lane q holds head q's 8 ch
    float inv = 1.f / den;
    float v[8];
#pragma unroll
    for (int c = 0; c < 8; ++c) {
      float t = acc[c] * inv + s_b1[q * 8 + c];
      v[c] = (t > 0.f) ? t : (__expf(t) - 1.f);   // ELU
    }
    // fused gemm2: partial h2[j] = sum_c v[c] * W2[q*8+c][j]
    float p[7] = {};
#pragma unroll
    for (int c = 0; c < 8; ++c) {
      const float* wr = &s_w2[(q * 8 + c) * 7];
#pragma unroll
      for (int j = 0; j < 7; ++j) p[j] = fmaf(v[c], wr[j], p[j]);
    }
#pragma unroll
    for (int off = 1; off < 8; off <<= 1) {
#pragma unroll
      for (int j = 0; j < 7; ++j) p[j] += __shfl_xor(p[j], off, 64);
    }
    if (q == 0) {
      float s = 0.f, d = 0.f;
      short8 row;
#pragma unroll
      for (int j = 0; j < 7; ++j) {
        row[j] = (short)f2bf(p[j]);
        s = fmaf(p[j], s_ss[j], s);
        d = fmaf(p[j], s_dd[j], d);
      }
      row[7] = (short)f2bf(s);            // a_src score packed in slot 7
      *(short8*)(H2b + (size_t)n * 8) = row;
      aD2[n] = d;
    }
  }
}

// ---------------- aggregation layer 2: wave per node, lanes split edges ----------------
__global__ __launch_bounds__(256) void k_agg2(const unsigned short* __restrict__ H2b,
                                              const float* __restrict__ aD2,
                                              const int* __restrict__ cnt,
                                              const int* __restrict__ csr,
                                              const float* __restrict__ b2,
                                              float* __restrict__ out) {
  const int wv = threadIdx.x >> 6, lane = threadIdx.x & 63;
  const int n = blockIdx.x * 4 + wv;
  if (n >= NN) return;
  const float adv = aD2[n];
  const int beg = n << 7;
  const int deg = cnt[n];
  float acc[7] = {};
  float den = 0.f;
  for (int j = lane; j < deg; j += 64) {
    int s = csr[beg + j];
    short8 hv = *(const short8*)(H2b + (size_t)s * 8);
    float e = bf2f((unsigned short)hv[7]) + adv;
    e = (e > 0.f) ? e : 0.2f * e;
    float wgt = __expf(e);
    den += wgt;
#pragma unroll
    for (int c = 0; c < 7; ++c)
      acc[c] = fmaf(wgt, bf2f((unsigned short)hv[c]), acc[c]);
  }
#pragma unroll
  for (int off = 32; off > 0; off >>= 1) {
    den += __shfl_xor(den, off, 64);
#pragma unroll
    for (int c = 0; c < 7; ++c) acc[c] += __shfl_xor(acc[c], off, 64);
  }
  if (lane == 0) {
    float inv = 1.f / den;
    float v[7];
    float m = -1e30f;
#pragma unroll
    for (int c = 0; c < 7; ++c) { v[c] = acc[c] * inv + b2[c]; m = fmaxf(m, v[c]); }
    float se = 0.f;
#pragma unroll
    for (int c = 0; c < 7; ++c) se += __expf(v[c] - m);
    float lse = m + __logf(se);
#pragma unroll
    for (int c = 0; c < 7; ++c) out[n * 7 + c] = v[c] - lse;
  }
}

extern "C" void kernel_launch(void* const* d_in, const int* in_sizes, int n_in,
                              void* d_out, int out_size, void* d_ws, size_t ws_size,
                              hipStream_t stream) {
  const float* x   = (const float*)d_in[0];
  const int*   ei  = (const int*)d_in[1];
  const float* W1  = (const float*)d_in[2];
  const float* as1 = (const float*)d_in[3];
  const float* ad1 = (const float*)d_in[4];
  const float* b1  = (const float*)d_in[5];
  const float* W2  = (const float*)d_in[6];
  const float* as2 = (const float*)d_in[7];
  const float* ad2 = (const float*)d_in[8];
  const float* b2  = (const float*)d_in[9];
  float* out = (float*)d_out;

  char* ws = (char*)d_ws;
  size_t off = 0;
  auto alloc = [&](size_t bytes) {
    void* p = ws + off;
    off += (bytes + 255) & ~(size_t)255;
    return p;
  };
  unsigned short* h1b = (unsigned short*)alloc((size_t)NN * 64 * 2);
  float* sc1    = (float*)alloc((size_t)NN * 8 * 4);
  float* dc1    = (float*)alloc((size_t)NN * 8 * 4);
  unsigned short* h2b = (unsigned short*)alloc((size_t)NN * 8 * 2);
  float* dc2    = (float*)alloc((size_t)NN * 4);
  int*   cnt    = (int*)alloc((size_t)NN * 4);
  int*   csr    = (int*)alloc((size_t)NN * CAP * 4);
  int*   histM  = (int*)alloc((size_t)SB1 * BINS * 4);
  int*   binS   = (int*)alloc((size_t)BINS * 4);
  int*   binE   = (int*)alloc((size_t)BINS * 4);
  unsigned int* binned = (unsigned int*)alloc((size_t)ET * 4);
  unsigned short* w1t = (unsigned short*)alloc((size_t)F1 * KPAD * 2);

  // prep: W1^T
  k_prep<<<(F1 * KPAD + 255) / 256, 256, 0, stream>>>(W1, w1t);

  // gemm1 (BM=64, B-from-L2, 8 blocks/CU) || B1 bucket histogram
  k_fuse1<<<G1B + SB1, 256, 0, stream>>>(x, w1t, h1b, ei, histM);

  // B2: offsets
  k_scanM<<<1, 256, 0, stream>>>(histM, binS, binE);

  // B3: bin edges (no global atomics)
  k_bin<<<SB1, 256, 0, stream>>>(ei, histM, binned);

  // att1 || B4 bucket-group -> padded CSR
  k_fuse2<<<A1B + NB4, 256, 0, stream>>>(h1b, as1, ad1, sc1, dc1,
                                         binned, binS, binE, cnt, csr);

  // agg1 + fused gemm2/att2
  k_agg1<<<(NN + 3) / 4, 256, 0, stream>>>(h1b, sc1, dc1, cnt, csr, b1,
                                           W2, as2, ad2, h2b, dc2);

  // agg2 + log_softmax
  k_agg2<<<(NN + 3) / 4, 256, 0, stream>>>(h2b, dc2, cnt, csr, b2, out);
}

// Round 26
// 419.347 us; speedup vs baseline: 1.0859x; 1.0755x over previous
//
#include <hip/hip_runtime.h>
#include <hip/hip_bf16.h>
#include <math.h>

#define NN 100000
#define EE 3200000
#define ET (EE + NN)          // edges incl. self loops
#define FIN 1433
#define KPAD 1440
#define NT 45                 // K tiles of 32
#define F1 64
#define F2 7
#define G1B 1563              // gemm1 blocks (ceil(NN/64))
#define CAP 128               // padded CSR capacity per node
#define BINS 200              // dst>>9 -> 0..195 (padded)
#define SB1 256               // binning blocks
#define CH_E 12891            // ceil(ET/SB1)
#define NB4 196               // bucket-group blocks ((NN+511)>>9)
#define A1B 3125              // att1 blocks (NN*8/256)

typedef __attribute__((ext_vector_type(8))) short short8;
typedef __attribute__((ext_vector_type(4))) float f32x4;
typedef __attribute__((address_space(3))) unsigned int u32_lds;
typedef __attribute__((address_space(1))) const unsigned int u32_glb;

static __device__ __forceinline__ unsigned short f2bf(float f) {
  __hip_bfloat16 h = __float2bfloat16(f);
  return *reinterpret_cast<unsigned short*>(&h);
}
static __device__ __forceinline__ float bf2f(unsigned short u) {
  return __uint_as_float((unsigned int)u << 16);
}

// ---------------- prep: W1^T bf16 (padded) ----------------
__global__ __launch_bounds__(256) void k_prep(const float* __restrict__ W1,
                                              unsigned short* __restrict__ WT) {
  int i = blockIdx.x * 256 + threadIdx.x;
  if (i < F1 * KPAD) {
    int c = i / KPAD, k = i - c * KPAD;
    WT[i] = f2bf((k < FIN) ? W1[k * F1 + c] : 0.f);
  }
}

// ---------------- fuse1: gemm1 BM=64 (blocks 0..G1B) || B1 bucket histogram ----------------
// BM=64, 4 waves, dbuf 24.6 KB -> 6 blocks/CU (measured best: R22 = 421 us).
#define BM 64
#define TILEA 8192            // 64 rows x 32 k x f32
#define TILEB 4096            // 64 cols x 32 k bf16
#define BUFB (TILEA + TILEB)  // 12288

__global__ __launch_bounds__(256) void k_fuse1(const float* __restrict__ X,
                                               const unsigned short* __restrict__ WT,
                                               unsigned short* __restrict__ Hb,
                                               const int* __restrict__ ei,
                                               int* __restrict__ histM) {
  if (blockIdx.x >= G1B) {
    // ---- B1: per-block LDS histogram of dst buckets (LDS atomics only) ----
    __shared__ int hist[BINS];
    const int b = blockIdx.x - G1B;
    for (int i = threadIdx.x; i < BINS; i += 256) hist[i] = 0;
    __syncthreads();
    const int e0 = b * CH_E, e1 = min(e0 + CH_E, ET);
    for (int e = e0 + threadIdx.x; e < e1; e += 256) {
      int dst = (e < EE) ? ei[EE + e] : (e - EE);
      atomicAdd(&hist[dst >> 9], 1);
    }
    __syncthreads();
    for (int i = threadIdx.x; i < BINS; i += 256) histM[b * BINS + i] = hist[i];
    return;
  }
  __shared__ __align__(16) char smem[2 * BUFB];
  const int tid = threadIdx.x;
  const int lane = tid & 63;
  const int wid = tid >> 6;
  const int row0 = blockIdx.x * BM;
  const int l15 = lane & 15, l4 = lane >> 4;

  // A staging: 64 rows x 8 chunks = 512 chunks; 2 per thread (q=0,1)
  const int lrq = tid >> 3;          // 0..31
  const int mq = tid & 7;            // lds 16-B chunk slot
  const char* Xb = (const char*)X;
  size_t aoff[2];
#pragma unroll
  for (int q = 0; q < 2; ++q) {
    int lr = q * 32 + lrq;
    int gr = row0 + lr; if (gr >= NN) gr = NN - 1;
    int c = mq ^ (lr & 7);           // source chunk (inverse swizzle)
    aoff[q] = (size_t)gr * (FIN * 4) + (size_t)c * 16;
  }
  const unsigned short* bsrc =
      WT + (tid >> 2) * KPAD + (((tid & 3) ^ ((tid >> 3) & 3)) << 3);

  f32x4 acc[4];
#pragma unroll
  for (int fc = 0; fc < 4; ++fc) acc[fc] = 0.f;

  auto gstage = [&](int k0, char* buf) {
#pragma unroll
    for (int q = 0; q < 2; ++q) {
      __builtin_amdgcn_global_load_lds(
          (u32_glb*)(Xb + aoff[q] + (size_t)k0 * 4),
          (u32_lds*)(buf + q * 4096 + wid * 1024), 16, 0, 0);
    }
  };

  gstage(0, smem);
  {
    short8 b0 = *(const short8*)(bsrc + 0);
    *(short8*)(smem + TILEA + tid * 16) = b0;
  }
  __syncthreads();

  int cur = 0;
  for (int t = 0; t < NT; ++t) {
    char* buf = smem + cur * BUFB;
    char* nbuf = smem + (cur ^ 1) * BUFB;
    const bool have_next = (t + 1 < NT);
    const bool tail = (t + 1 == NT - 1);
    short8 bnext;
    f32x4 atail[2];
    if (have_next) {
      if (!tail) {
        gstage((t + 1) * 32, nbuf);
      } else {
        // last k-tile (k0=1408): predicated register path (avoids OOB)
#pragma unroll
        for (int q = 0; q < 2; ++q) {
          int lr = q * 32 + lrq;
          int gr = row0 + lr; if (gr >= NN) gr = NN - 1;
          int c = mq ^ (lr & 7);
          int kb = (NT - 1) * 32 + c * 4;
          const float* xp = X + (size_t)gr * FIN + kb;
#pragma unroll
          for (int j = 0; j < 4; ++j)
            atail[q][j] = (kb + j < FIN) ? xp[j] : 0.f;
        }
      }
      bnext = *(const short8*)(bsrc + (t + 1) * 32);
    }

    // A frag: row = wid*16 + l15, source chunks 2*l4, 2*l4+1 (swizzled slots)
    short8 a;
    {
      const int r = wid * 16 + l15;
      const int sz = l15 & 7;       // r&7 == l15&7
      f32x4 a0 = *(const f32x4*)(buf + r * 128 + ((2 * l4) ^ sz) * 16);
      f32x4 a1 = *(const f32x4*)(buf + r * 128 + ((2 * l4 + 1) ^ sz) * 16);
#pragma unroll
      for (int j = 0; j < 4; ++j) {
        a[j] = (short)f2bf(a0[j]);
        a[4 + j] = (short)f2bf(a1[j]);
      }
    }
#pragma unroll
    for (int fc = 0; fc < 4; ++fc) {
      int c = fc * 16 + l15;
      int jp = l4 ^ ((c >> 1) & 3);
      short8 b = *(const short8*)(buf + TILEA + c * 64 + jp * 16);
      acc[fc] = __builtin_amdgcn_mfma_f32_16x16x32_bf16(a, b, acc[fc], 0, 0, 0);
    }

    if (have_next) {
      if (tail) {
#pragma unroll
        for (int q = 0; q < 2; ++q)
          *(f32x4*)(nbuf + (q * 32 + lrq) * 128 + mq * 16) = atail[q];
      }
      *(short8*)(nbuf + TILEA + tid * 16) = bnext;
    }
    __syncthreads();
    cur ^= 1;
  }

  // epilogue: C/D layout col=lane&15, row=(lane>>4)*4+reg; store bf16
  const int rbase = row0 + wid * 16 + l4 * 4;
#pragma unroll
  for (int j = 0; j < 4; ++j) {
    int r = rbase + j;
    if (r < NN) {
#pragma unroll
      for (int fc = 0; fc < 4; ++fc)
        Hb[(size_t)r * F1 + fc * 16 + l15] = f2bf(acc[fc][j]);
    }
  }
}

// ---------------- B2: scan histM -> exact per-(block,bin) offsets ----------------
__global__ __launch_bounds__(256) void k_scanM(int* __restrict__ histM,
                                               int* __restrict__ binS,
                                               int* __restrict__ binE) {
  __shared__ int s[256];
  const int t = threadIdx.x;
  int total = 0;
  if (t < BINS)
    for (int b = 0; b < SB1; ++b) total += histM[b * BINS + t];
  s[t] = total;
  __syncthreads();
  for (int off = 1; off < 256; off <<= 1) {
    int v = s[t];
    int u = (t >= off) ? s[t - off] : 0;
    __syncthreads();
    s[t] = v + u;
    __syncthreads();
  }
  if (t < BINS) {
    int run = s[t] - total;            // exclusive prefix
    binS[t] = run;
    for (int b = 0; b < SB1; ++b) {
      int h = histM[b * BINS + t];
      histM[b * BINS + t] = run;
      run += h;
    }
    binE[t] = run;
  }
}

// ---------------- B3: bin edges (plain stores, LDS cursors) ----------------
__global__ __launch_bounds__(256) void k_bin(const int* __restrict__ ei,
                                             const int* __restrict__ histM,
                                             unsigned int* __restrict__ binned) {
  __shared__ int cur[BINS];
  const int b = blockIdx.x;
  for (int i = threadIdx.x; i < BINS; i += 256) cur[i] = histM[b * BINS + i];
  __syncthreads();
  const int e0 = b * CH_E, e1 = min(e0 + CH_E, ET);
  for (int e = e0 + threadIdx.x; e < e1; e += 256) {
    int dst = (e < EE) ? ei[EE + e] : (e - EE);
    int src = (e < EE) ? ei[e] : dst;
    int pos = atomicAdd(&cur[dst >> 9], 1);        // LDS atomic
    binned[pos] = ((unsigned)(dst & 511) << 17) | (unsigned)src;
  }
}

// ---------------- fuse2: att1 (blocks 0..A1B) || B4 bucket-group ----------------
__global__ __launch_bounds__(256) void k_fuse2(const unsigned short* __restrict__ Hb,
                                               const float* __restrict__ attS,
                                               const float* __restrict__ attD,
                                               float* __restrict__ aS,
                                               float* __restrict__ aD,
                                               const unsigned int* __restrict__ binned,
                                               const int* __restrict__ binS,
                                               const int* __restrict__ binE,
                                               int* __restrict__ cnt,
                                               int* __restrict__ csr) {
  if (blockIdx.x >= A1B) {
    // ---- B4: group one bucket's edges into padded CSR (LDS atomics only) ----
    __shared__ int lcnt[512];
    const int g = blockIdx.x - A1B;
    for (int i = threadIdx.x; i < 512; i += 256) lcnt[i] = 0;
    __syncthreads();
    const int s0 = binS[g], s1 = binE[g];
    const int nbase = g << 9;
    for (int i = s0 + threadIdx.x; i < s1; i += 256) {
      unsigned v = binned[i];
      int ld = v >> 17;
      int src = (int)(v & 0x1FFFFu);
      int pos = atomicAdd(&lcnt[ld], 1);           // LDS atomic
      csr[((size_t)(nbase + ld) << 7) + pos] = src;
    }
    __syncthreads();
    for (int i = threadIdx.x; i < 512; i += 256) {
      int n = nbase + i;
      if (n < NN) cnt[n] = lcnt[i];
    }
    return;
  }
  // ---- att1: per-node attention scores (8 threads/node) ----
  __shared__ float s_s[64], s_d[64];
  if (threadIdx.x < 64) { s_s[threadIdx.x] = attS[threadIdx.x]; s_d[threadIdx.x] = attD[threadIdx.x]; }
  __syncthreads();
  int idx = blockIdx.x * 256 + threadIdx.x;
  int n = idx >> 3, h = idx & 7;
  if (n >= NN) return;
  short8 v8 = *(const short8*)(Hb + (size_t)n * 64 + h * 8);
  float ss = 0.f, dd = 0.f;
#pragma unroll
  for (int c = 0; c < 8; ++c) {
    float v = bf2f((unsigned short)v8[c]);
    ss = fmaf(v, s_s[h * 8 + c], ss);
    dd = fmaf(v, s_d[h * 8 + c], dd);
  }
  aS[n * 8 + h] = ss;
  aD[n * 8 + h] = dd;
}

// ---------------- agg1 + fused gemm2/att2: wave per node, 8 edges x 8 heads ----
__global__ __launch_bounds__(256) void k_agg1(const unsigned short* __restrict__ Hb,
                                              const float* __restrict__ aS,
                                              const float* __restrict__ aD,
                                              const int* __restrict__ cnt,
                                              const int* __restrict__ csr,
                                              const float* __restrict__ b1,
                                              const float* __restrict__ W2,
                                              const float* __restrict__ s2,
                                              const float* __restrict__ d2,
                                              unsigned short* __restrict__ H2b,
                                              float* __restrict__ aD2) {
  __shared__ float s_w2[448];
  __shared__ float s_ss[7], s_dd[7];
  __shared__ float s_b1[64];
  for (int i = threadIdx.x; i < 448; i += 256) s_w2[i] = W2[i];
  if (threadIdx.x < 7) { s_ss[threadIdx.x] = s2[threadIdx.x]; s_dd[threadIdx.x] = d2[threadIdx.x]; }
  if (threadIdx.x < 64) s_b1[threadIdx.x] = b1[threadIdx.x];
  __syncthreads();

  const int wv = threadIdx.x >> 6, lane = threadIdx.x & 63;
  const int n = blockIdx.x * 4 + wv;
  if (n >= NN) return;
  const int eg = lane >> 3, q = lane & 7;
  const float adv = aD[n * 8 + q];
  const int beg = n << 7;
  const int deg = cnt[n];
  float acc[8] = {};
  float den = 0.f;
#pragma unroll 2
  for (int i = eg; i < deg; i += 8) {
    int s = csr[beg + i];                 // broadcast within eg-group
    float e = aS[s * 8 + q] + adv;
    e = (e > 0.f) ? e : 0.2f * e;         // leaky_relu
    float w = __expf(e);                  // max-shift unnecessary (|e| bounded)
    den += w;
    short8 hv = *(const short8*)(Hb + (size_t)s * 64 + q * 8);
#pragma unroll
    for (int c = 0; c < 8; ++c)
      acc[c] = fmaf(w, bf2f((unsigned short)hv[c]), acc[c]);
  }
#pragma unroll
  for (int off = 8; off < 64; off <<= 1) {
    den += __shfl_xor(den, off, 64);
#pragma unroll
    for (int c = 0; c < 8; ++c) acc[c] += __shfl_xor(acc[c], off, 64);
  }
  if (eg == 0) {                          // lanes 0..7: lane q holds head q's 8 ch
    float inv = 1.f / den;
    float v[8];
#pragma unroll
    for (int c = 0; c < 8; ++c) {
      float t = acc[c] * inv + s_b1[q * 8 + c];
      v[c] = (t > 0.f) ? t : (__expf(t) - 1.f);   // ELU
    }
    // fused gemm2: partial h2[j] = sum_c v[c] * W2[q*8+c][j]
    float p[7] = {};
#pragma unroll
    for (int c = 0; c < 8; ++c) {
      const float* wr = &s_w2[(q * 8 + c) * 7];
#pragma unroll
      for (int j = 0; j < 7; ++j) p[j] = fmaf(v[c], wr[j], p[j]);
    }
#pragma unroll
    for (int off = 1; off < 8; off <<= 1) {
#pragma unroll
      for (int j = 0; j < 7; ++j) p[j] += __shfl_xor(p[j], off, 64);
    }
    if (q == 0) {
      float s = 0.f, d = 0.f;
      short8 row;
#pragma unroll
      for (int j = 0; j < 7; ++j) {
        row[j] = (short)f2bf(p[j]);
        s = fmaf(p[j], s_ss[j], s);
        d = fmaf(p[j], s_dd[j], d);
      }
      row[7] = (short)f2bf(s);            // a_src score packed in slot 7
      *(short8*)(H2b + (size_t)n * 8) = row;
      aD2[n] = d;
    }
  }
}

// ---------------- aggregation layer 2: wave per node, lanes split edges ----------------
__global__ __launch_bounds__(256) void k_agg2(const unsigned short* __restrict__ H2b,
                                              const float* __restrict__ aD2,
                                              const int* __restrict__ cnt,
                                              const int* __restrict__ csr,
                                              const float* __restrict__ b2,
                                              float* __restrict__ out) {
  const int wv = threadIdx.x >> 6, lane = threadIdx.x & 63;
  const int n = blockIdx.x * 4 + wv;
  if (n >= NN) return;
  const float adv = aD2[n];
  const int beg = n << 7;
  const int deg = cnt[n];
  float acc[7] = {};
  float den = 0.f;
  for (int j = lane; j < deg; j += 64) {
    int s = csr[beg + j];
    short8 hv = *(const short8*)(H2b + (size_t)s * 8);
    float e = bf2f((unsigned short)hv[7]) + adv;
    e = (e > 0.f) ? e : 0.2f * e;
    float wgt = __expf(e);
    den += wgt;
#pragma unroll
    for (int c = 0; c < 7; ++c)
      acc[c] = fmaf(wgt, bf2f((unsigned short)hv[c]), acc[c]);
  }
#pragma unroll
  for (int off = 32; off > 0; off >>= 1) {
    den += __shfl_xor(den, off, 64);
#pragma unroll
    for (int c = 0; c < 7; ++c) acc[c] += __shfl_xor(acc[c], off, 64);
  }
  if (lane == 0) {
    float inv = 1.f / den;
    float v[7];
    float m = -1e30f;
#pragma unroll
    for (int c = 0; c < 7; ++c) { v[c] = acc[c] * inv + b2[c]; m = fmaxf(m, v[c]); }
    float se = 0.f;
#pragma unroll
    for (int c = 0; c < 7; ++c) se += __expf(v[c] - m);
    float lse = m + __logf(se);
#pragma unroll
    for (int c = 0; c < 7; ++c) out[n * 7 + c] = v[c] - lse;
  }
}

extern "C" void kernel_launch(void* const* d_in, const int* in_sizes, int n_in,
                              void* d_out, int out_size, void* d_ws, size_t ws_size,
                              hipStream_t stream) {
  const float* x   = (const float*)d_in[0];
  const int*   ei  = (const int*)d_in[1];
  const float* W1  = (const float*)d_in[2];
  const float* as1 = (const float*)d_in[3];
  const float* ad1 = (const float*)d_in[4];
  const float* b1  = (const float*)d_in[5];
  const float* W2  = (const float*)d_in[6];
  const float* as2 = (const float*)d_in[7];
  const float* ad2 = (const float*)d_in[8];
  const float* b2  = (const float*)d_in[9];
  float* out = (float*)d_out;

  char* ws = (char*)d_ws;
  size_t off = 0;
  auto alloc = [&](size_t bytes) {
    void* p = ws + off;
    off += (bytes + 255) & ~(size_t)255;
    return p;
  };
  unsigned short* h1b = (unsigned short*)alloc((size_t)NN * 64 * 2);
  float* sc1    = (float*)alloc((size_t)NN * 8 * 4);
  float* dc1    = (float*)alloc((size_t)NN * 8 * 4);
  unsigned short* h2b = (unsigned short*)alloc((size_t)NN * 8 * 2);
  float* dc2    = (float*)alloc((size_t)NN * 4);
  int*   cnt    = (int*)alloc((size_t)NN * 4);
  int*   csr    = (int*)alloc((size_t)NN * CAP * 4);
  int*   histM  = (int*)alloc((size_t)SB1 * BINS * 4);
  int*   binS   = (int*)alloc((size_t)BINS * 4);
  int*   binE   = (int*)alloc((size_t)BINS * 4);
  unsigned int* binned = (unsigned int*)alloc((size_t)ET * 4);
  unsigned short* w1t = (unsigned short*)alloc((size_t)F1 * KPAD * 2);

  // prep: W1^T
  k_prep<<<(F1 * KPAD + 255) / 256, 256, 0, stream>>>(W1, w1t);

  // gemm1 (BM=64, 6 blocks/CU) || B1 bucket histogram
  k_fuse1<<<G1B + SB1, 256, 0, stream>>>(x, w1t, h1b, ei, histM);

  // B2: offsets
  k_scanM<<<1, 256, 0, stream>>>(histM, binS, binE);

  // B3: bin edges (no global atomics)
  k_bin<<<SB1, 256, 0, stream>>>(ei, histM, binned);

  // att1 || B4 bucket-group -> padded CSR
  k_fuse2<<<A1B + NB4, 256, 0, stream>>>(h1b, as1, ad1, sc1, dc1,
                                         binned, binS, binE, cnt, csr);

  // agg1 + fused gemm2/att2
  k_agg1<<<(NN + 3) / 4, 256, 0, stream>>>(h1b, sc1, dc1, cnt, csr, b1,
                                           W2, as2, ad2, h2b, dc2);

  // agg2 + log_softmax
  k_agg2<<<(NN + 3) / 4, 256, 0, stream>>>(h2b, dc2, cnt, csr, b2, out);
}